// Round 2
// baseline (158.830 us; speedup 1.0000x reference)
//
#include <hip/hip_runtime.h>
#include <hip/hip_bf16.h>

typedef _Float16 f16;
typedef _Float16 f16x8 __attribute__((ext_vector_type(8)));
typedef float f32x4 __attribute__((ext_vector_type(4)));

#define NN 200000
#define KK 512
#define CC 64
#define JJ 32
// W_frag: 48 F-ksteps (16 w1 | 16 wh | 16 wl) x 4 coltiles x 64 lanes x 8 f16
#define WFRAG_ELEMS (48 * 4 * 64 * 8) /* 98304 f16 = 192 KiB */

// Pack W into MFMA-B fragment order: elem idx = ((kF*4 + ct)*64 + lane)*8 + i
// holds W[Fk = (kF&15)*32 + (lane>>4)*8 + i][c = ct*16 + (lane&15)], section kF>>4:
//   0: w1 = -0.5*(exp(-lv)-1)   (vs xx, centered variance term)
//   1: wh = f16(mu*exp(-lv))    (vs xh and xl)
//   2: wl = residual of wh      (vs xh)
__global__ __launch_bounds__(256) void fill_w(const float* __restrict__ mu,
                                              const float* __restrict__ lv,
                                              f16* __restrict__ wfrag) {
  int idx = blockIdx.x * 256 + threadIdx.x;
  int i = idx & 7, l = (idx >> 3) & 63, ct = (idx >> 9) & 3, kF = idx >> 11;
  int k = (kF & 15) * 32 + (l >> 4) * 8 + i;
  int c = ct * 16 + (l & 15);
  int sec = kF >> 4;
  float lvv = lv[c * KK + k];
  float w;
  if (sec == 0) {
    w = -0.5f * expm1f(-lvv);
  } else {
    float w2 = mu[c * KK + k] * expf(-lvv);
    float wh = (float)(f16)w2;
    w = (sec == 1) ? wh : (w2 - wh);
  }
  wfrag[idx] = (f16)w;
}

// bias[j][c] = log(alpha*beta[c] + njk[j][c]) - 0.5*(sum_k(mu^2*iv + lv) + K*ln(2pi))
__global__ __launch_bounds__(64) void fill_bias(const float* __restrict__ mu,
                                                const float* __restrict__ lv,
                                                const float* __restrict__ beta,
                                                const float* __restrict__ njk,
                                                const float* __restrict__ alphap,
                                                float* __restrict__ bias) {
  int c = blockIdx.x;
  int lane = threadIdx.x;
  float s = 0.0f;
  for (int k = lane; k < KK; k += 64) {
    float l2 = lv[c * KK + k];
    float m = mu[c * KK + k];
    s += fmaf(m * m, expf(-l2), l2);
  }
  #pragma unroll
  for (int d = 1; d < 64; d <<= 1) s += __shfl_xor(s, d, 64);
  float base = -0.5f * (s + 512.0f * 1.8378770664093453f);
  if (lane < JJ)
    bias[lane * CC + c] = logf(alphap[0] * beta[c] + njk[lane * CC + c]) + base;
}

// 256-thread blocks = 4 independent waves, each owning a 32-row tile (no LDS,
// no barriers). Explicit x double-buffer; JIT B-frag loads (L2-resident).
// Layouts (m89-verified): A row=l&15, k=(l>>4)*8+i; D col=l&15, row=(l>>4)*4+reg.
__global__ __launch_bounds__(256, 4) void gmm_main(
    const float* __restrict__ x, const int* __restrict__ ms,
    const f16* __restrict__ wfrag, const float* __restrict__ bias,
    float* __restrict__ out) {
  const int lane = threadIdx.x & 63;
  const int wv = threadIdx.x >> 6;
  const int lr = lane & 15;   // A row / D col / B col within tile
  const int kg = lane >> 4;   // k-group (8 consecutive k each)
  const int row0 = blockIdx.x * 128 + wv * 32;
  if (row0 >= NN) return;

  f32x4 acc[2][4];
  #pragma unroll
  for (int rt = 0; rt < 2; ++rt)
    #pragma unroll
    for (int ct = 0; ct < 4; ++ct) acc[rt][ct] = (f32x4)0.0f;

  const float* xp0 = x + (size_t)(row0 + lr) * KK + kg * 8;
  const float* xp1 = xp0 + (size_t)16 * KK;
  const f16* wb = wfrag + lane * 8;

  // cx[0..1] = row-tile 0 (8 floats), cx[2..3] = row-tile 1
  f32x4 cx[4];
  cx[0] = __builtin_nontemporal_load(reinterpret_cast<const f32x4*>(xp0));
  cx[1] = __builtin_nontemporal_load(reinterpret_cast<const f32x4*>(xp0 + 4));
  cx[2] = __builtin_nontemporal_load(reinterpret_cast<const f32x4*>(xp1));
  cx[3] = __builtin_nontemporal_load(reinterpret_cast<const f32x4*>(xp1 + 4));

  #pragma unroll 1
  for (int s = 0; s < 16; ++s) {
    // prefetch s+1 while computing s
    f32x4 nx[4];
    if (s < 15) {
      const float* p0 = xp0 + (s + 1) * 32;
      const float* p1 = xp1 + (s + 1) * 32;
      nx[0] = __builtin_nontemporal_load(reinterpret_cast<const f32x4*>(p0));
      nx[1] = __builtin_nontemporal_load(reinterpret_cast<const f32x4*>(p0 + 4));
      nx[2] = __builtin_nontemporal_load(reinterpret_cast<const f32x4*>(p1));
      nx[3] = __builtin_nontemporal_load(reinterpret_cast<const f32x4*>(p1 + 4));
    }

    f16x8 fxx[2], fxh[2], fxl[2];
    #pragma unroll
    for (int rt = 0; rt < 2; ++rt) {
      #pragma unroll
      for (int i = 0; i < 8; ++i) {
        float v = (i < 4) ? cx[rt * 2][i] : cx[rt * 2 + 1][i - 4];
        f16 h = (f16)v;
        fxh[rt][i] = h;
        fxl[rt][i] = (f16)(v - (float)h);
        fxx[rt][i] = (f16)(v * v);
      }
    }

    const f16* wbs = wb + (size_t)s * 2048;  // s-stride: 4ct*64lane*8 f16
    #pragma unroll
    for (int ct = 0; ct < 4; ++ct) {
      f16x8 bw1 = *reinterpret_cast<const f16x8*>(wbs + ct * 512);
      f16x8 bwh = *reinterpret_cast<const f16x8*>(wbs + 32768 + ct * 512);
      f16x8 bwl = *reinterpret_cast<const f16x8*>(wbs + 65536 + ct * 512);
      #pragma unroll
      for (int rt = 0; rt < 2; ++rt) {
        acc[rt][ct] = __builtin_amdgcn_mfma_f32_16x16x32_f16(fxx[rt], bw1, acc[rt][ct], 0, 0, 0);
        acc[rt][ct] = __builtin_amdgcn_mfma_f32_16x16x32_f16(fxh[rt], bwh, acc[rt][ct], 0, 0, 0);
        acc[rt][ct] = __builtin_amdgcn_mfma_f32_16x16x32_f16(fxh[rt], bwl, acc[rt][ct], 0, 0, 0);
        acc[rt][ct] = __builtin_amdgcn_mfma_f32_16x16x32_f16(fxl[rt], bwh, acc[rt][ct], 0, 0, 0);
      }
    }

    if (s < 15) {
      cx[0] = nx[0]; cx[1] = nx[1]; cx[2] = nx[2]; cx[3] = nx[3];
    }
  }

  // Epilogue: bias add + softmax across 64 cols (4 regs x 16 lanes) + store.
  #pragma unroll
  for (int rt = 0; rt < 2; ++rt) {
    int rbase = row0 + rt * 16 + kg * 4;
    #pragma unroll
    for (int r = 0; r < 4; ++r) {
      int j = ms[rbase + r];
      const float* bj = bias + j * CC + lr;
      float v0 = acc[rt][0][r] + bj[0];
      float v1 = acc[rt][1][r] + bj[16];
      float v2 = acc[rt][2][r] + bj[32];
      float v3 = acc[rt][3][r] + bj[48];
      float m = fmaxf(fmaxf(v0, v1), fmaxf(v2, v3));
      #pragma unroll
      for (int d = 1; d < 16; d <<= 1) m = fmaxf(m, __shfl_xor(m, d, 64));
      float e0 = __expf(v0 - m), e1 = __expf(v1 - m);
      float e2 = __expf(v2 - m), e3 = __expf(v3 - m);
      float sum = (e0 + e1) + (e2 + e3);
      #pragma unroll
      for (int d = 1; d < 16; d <<= 1) sum += __shfl_xor(sum, d, 64);
      float inv = 1.0f / sum;
      float* o = out + (size_t)(rbase + r) * CC + lr;
      __builtin_nontemporal_store(e0 * inv, o);
      __builtin_nontemporal_store(e1 * inv, o + 16);
      __builtin_nontemporal_store(e2 * inv, o + 32);
      __builtin_nontemporal_store(e3 * inv, o + 48);
    }
  }
}

extern "C" void kernel_launch(void* const* d_in, const int* in_sizes, int n_in,
                              void* d_out, int out_size, void* d_ws, size_t ws_size,
                              hipStream_t stream) {
  const float* x     = (const float*)d_in[0];
  const float* mu    = (const float*)d_in[1];
  const float* lv    = (const float*)d_in[2];
  const float* beta  = (const float*)d_in[3];
  const float* njk   = (const float*)d_in[4];
  const float* alpha = (const float*)d_in[5];
  const int*   ms    = (const int*)d_in[6];
  float* out = (float*)d_out;

  f16* wfrag  = (f16*)d_ws;
  float* bias = (float*)((char*)d_ws + WFRAG_ELEMS * sizeof(f16));

  fill_w<<<WFRAG_ELEMS / 256, 256, 0, stream>>>(mu, lv, wfrag);
  fill_bias<<<CC, 64, 0, stream>>>(mu, lv, beta, njk, alpha, bias);
  gmm_main<<<(NN + 127) / 128, 256, 0, stream>>>(x, ms, wfrag, bias, out);
}

// Round 3
// 129.799 us; speedup vs baseline: 1.2237x; 1.2237x over previous
//
#include <hip/hip_runtime.h>
#include <hip/hip_bf16.h>

typedef _Float16 f16;
typedef _Float16 f16x8 __attribute__((ext_vector_type(8)));
typedef float f32x4 __attribute__((ext_vector_type(4)));

#define NN 200000
#define KK 512
#define CC 64
#define JJ 32
// W_frag: 48 F-ksteps (16 w1 | 16 wh | 16 wl) x 4 coltiles x 64 lanes x 8 f16
#define WFRAG_ELEMS (48 * 4 * 64 * 8) /* 98304 f16 = 192 KiB */

__device__ inline void gload_lds16(const void* g, void* l) {
  __builtin_amdgcn_global_load_lds(
      (const __attribute__((address_space(1))) void*)g,
      (__attribute__((address_space(3))) void*)l, 16, 0, 0);
}

// Pack W into MFMA-B fragment order: elem idx = ((kF*4 + ct)*64 + lane)*8 + i
// holds W[Fk = (kF&15)*32 + (lane>>4)*8 + i][c = ct*16 + (lane&15)], section kF>>4:
//   0: w1 = -0.5*(exp(-lv)-1)   (vs xx, centered variance term)
//   1: wh = f16(mu*exp(-lv))    (vs xh and xl)
//   2: wl = residual of wh      (vs xh)
__global__ __launch_bounds__(256) void fill_w(const float* __restrict__ mu,
                                              const float* __restrict__ lv,
                                              f16* __restrict__ wfrag) {
  int idx = blockIdx.x * 256 + threadIdx.x;
  int i = idx & 7, l = (idx >> 3) & 63, ct = (idx >> 9) & 3, kF = idx >> 11;
  int k = (kF & 15) * 32 + (l >> 4) * 8 + i;
  int c = ct * 16 + (l & 15);
  int sec = kF >> 4;
  float lvv = lv[c * KK + k];
  float w;
  if (sec == 0) {
    w = -0.5f * expm1f(-lvv);
  } else {
    float w2 = mu[c * KK + k] * expf(-lvv);
    float wh = (float)(f16)w2;
    w = (sec == 1) ? wh : (w2 - wh);
  }
  wfrag[idx] = (f16)w;
}

// bias[j][c] = log(alpha*beta[c] + njk[j][c]) - 0.5*(sum_k(mu^2*iv + lv) + K*ln(2pi))
__global__ __launch_bounds__(64) void fill_bias(const float* __restrict__ mu,
                                                const float* __restrict__ lv,
                                                const float* __restrict__ beta,
                                                const float* __restrict__ njk,
                                                const float* __restrict__ alphap,
                                                float* __restrict__ bias) {
  int c = blockIdx.x;
  int lane = threadIdx.x;
  float s = 0.0f;
  for (int k = lane; k < KK; k += 64) {
    float l2 = lv[c * KK + k];
    float m = mu[c * KK + k];
    s += fmaf(m * m, expf(-l2), l2);
  }
  #pragma unroll
  for (int d = 1; d < 64; d <<= 1) s += __shfl_xor(s, d, 64);
  float base = -0.5f * (s + 512.0f * 1.8378770664093453f);
  if (lane < JJ)
    bias[lane * CC + c] = logf(alphap[0] * beta[c] + njk[lane * CC + c]) + base;
}

// 4-wave workgroup, 128 rows/wg (32 rows per wave). Per s-step the workgroup
// stages the 12 KiB W-frag chunk into double-buffered LDS (global_load_lds,
// linear dest == frag order), shared by all 4 waves: W L2 traffic /4.
// Layouts (m89-verified): A row=l&15, k=(l>>4)*8+i; D col=l&15, row=(l>>4)*4+reg.
__global__ __launch_bounds__(256, 3) void gmm_main(
    const float* __restrict__ x, const int* __restrict__ ms,
    const f16* __restrict__ wfrag, const float* __restrict__ bias,
    float* __restrict__ out) {
  __shared__ char lds[2 * 12288];
  const int t = threadIdx.x;
  const int lane = t & 63;
  const int wv = t >> 6;
  const int lr = lane & 15;   // A row / D col / B col within tile
  const int kg = lane >> 4;   // k-group (8 consecutive k each)
  const long row0 = (long)blockIdx.x * 128 + wv * 32;
  const bool valid = row0 < NN;            // last wg: waves 2,3 idle but stay for barriers
  const long r0 = valid ? row0 + lr : 0;
  const long r1 = valid ? row0 + 16 + lr : 0;

  const float* xp0 = x + r0 * KK + kg * 8;
  const float* xp1 = x + r1 * KK + kg * 8;
  const char* wfb = (const char*)wfrag;
  const int lsec = wv * 1024 + lane * 16;  // this thread's 16B slot within a 4 KiB sec-chunk

  f32x4 acc[2][4];
  #pragma unroll
  for (int rt = 0; rt < 2; ++rt)
    #pragma unroll
    for (int ct = 0; ct < 4; ++ct) acc[rt][ct] = (f32x4)0.0f;

  // prologue: stage s=0 into buf0; load s=0 x
  #pragma unroll
  for (int sec = 0; sec < 3; ++sec)
    gload_lds16(wfb + sec * 65536 + lsec, lds + sec * 4096 + wv * 1024);

  f32x4 cx[4];
  cx[0] = __builtin_nontemporal_load(reinterpret_cast<const f32x4*>(xp0));
  cx[1] = __builtin_nontemporal_load(reinterpret_cast<const f32x4*>(xp0 + 4));
  cx[2] = __builtin_nontemporal_load(reinterpret_cast<const f32x4*>(xp1));
  cx[3] = __builtin_nontemporal_load(reinterpret_cast<const f32x4*>(xp1 + 4));
  __syncthreads();

  int cur = 0;
  #pragma unroll 1
  for (int s = 0; s < 16; ++s) {
    // stage s+1 into the other buffer; prefetch next x
    f32x4 nx[4];
    if (s < 15) {
      const char* gsrc = wfb + (s + 1) * 4096;
      char* ldst = lds + (cur ^ 1) * 12288;
      #pragma unroll
      for (int sec = 0; sec < 3; ++sec)
        gload_lds16(gsrc + sec * 65536 + lsec, ldst + sec * 4096 + wv * 1024);
      const float* p0 = xp0 + (s + 1) * 32;
      const float* p1 = xp1 + (s + 1) * 32;
      nx[0] = __builtin_nontemporal_load(reinterpret_cast<const f32x4*>(p0));
      nx[1] = __builtin_nontemporal_load(reinterpret_cast<const f32x4*>(p0 + 4));
      nx[2] = __builtin_nontemporal_load(reinterpret_cast<const f32x4*>(p1));
      nx[3] = __builtin_nontemporal_load(reinterpret_cast<const f32x4*>(p1 + 4));
    }

    // convert current x to f16 hi/lo/square fragments
    f16x8 fxx[2], fxh[2], fxl[2];
    #pragma unroll
    for (int rt = 0; rt < 2; ++rt) {
      #pragma unroll
      for (int i = 0; i < 8; ++i) {
        float v = (i < 4) ? cx[rt * 2][i] : cx[rt * 2 + 1][i - 4];
        f16 h = (f16)v;
        fxh[rt][i] = h;
        fxl[rt][i] = (f16)(v - (float)h);
        fxx[rt][i] = (f16)(v * v);
      }
    }

    // B-frags from LDS (16B/lane contiguous -> conflict-free ds_read_b128)
    const f16* lbase = (const f16*)(lds + cur * 12288) + lane * 8;
    #pragma unroll
    for (int ct = 0; ct < 4; ++ct) {
      f16x8 bw1 = *reinterpret_cast<const f16x8*>(lbase + ct * 512);
      f16x8 bwh = *reinterpret_cast<const f16x8*>(lbase + 2048 + ct * 512);
      f16x8 bwl = *reinterpret_cast<const f16x8*>(lbase + 4096 + ct * 512);
      #pragma unroll
      for (int rt = 0; rt < 2; ++rt) {
        acc[rt][ct] = __builtin_amdgcn_mfma_f32_16x16x32_f16(fxx[rt], bw1, acc[rt][ct], 0, 0, 0);
        acc[rt][ct] = __builtin_amdgcn_mfma_f32_16x16x32_f16(fxh[rt], bwh, acc[rt][ct], 0, 0, 0);
        acc[rt][ct] = __builtin_amdgcn_mfma_f32_16x16x32_f16(fxh[rt], bwl, acc[rt][ct], 0, 0, 0);
        acc[rt][ct] = __builtin_amdgcn_mfma_f32_16x16x32_f16(fxl[rt], bwh, acc[rt][ct], 0, 0, 0);
      }
    }

    __syncthreads();  // staged buf complete + all reads of cur done
    cur ^= 1;
    if (s < 15) {
      cx[0] = nx[0]; cx[1] = nx[1]; cx[2] = nx[2]; cx[3] = nx[3];
    }
  }

  // Epilogue: bias add + softmax across 64 cols (4 regs x 16 lanes) + store.
  if (valid) {
    #pragma unroll
    for (int rt = 0; rt < 2; ++rt) {
      long rbase = row0 + rt * 16 + kg * 4;
      #pragma unroll
      for (int r = 0; r < 4; ++r) {
        int j = ms[rbase + r];
        const float* bj = bias + j * CC + lr;
        float v0 = acc[rt][0][r] + bj[0];
        float v1 = acc[rt][1][r] + bj[16];
        float v2 = acc[rt][2][r] + bj[32];
        float v3 = acc[rt][3][r] + bj[48];
        float m = fmaxf(fmaxf(v0, v1), fmaxf(v2, v3));
        #pragma unroll
        for (int d = 1; d < 16; d <<= 1) m = fmaxf(m, __shfl_xor(m, d, 64));
        float e0 = __expf(v0 - m), e1 = __expf(v1 - m);
        float e2 = __expf(v2 - m), e3 = __expf(v3 - m);
        float sum = (e0 + e1) + (e2 + e3);
        #pragma unroll
        for (int d = 1; d < 16; d <<= 1) sum += __shfl_xor(sum, d, 64);
        float inv = 1.0f / sum;
        float* o = out + (size_t)rbase * CC + r * CC + lr;
        __builtin_nontemporal_store(e0 * inv, o);
        __builtin_nontemporal_store(e1 * inv, o + 16);
        __builtin_nontemporal_store(e2 * inv, o + 32);
        __builtin_nontemporal_store(e3 * inv, o + 48);
      }
    }
  }
}

extern "C" void kernel_launch(void* const* d_in, const int* in_sizes, int n_in,
                              void* d_out, int out_size, void* d_ws, size_t ws_size,
                              hipStream_t stream) {
  const float* x     = (const float*)d_in[0];
  const float* mu    = (const float*)d_in[1];
  const float* lv    = (const float*)d_in[2];
  const float* beta  = (const float*)d_in[3];
  const float* njk   = (const float*)d_in[4];
  const float* alpha = (const float*)d_in[5];
  const int*   ms    = (const int*)d_in[6];
  float* out = (float*)d_out;

  f16* wfrag  = (f16*)d_ws;
  float* bias = (float*)((char*)d_ws + WFRAG_ELEMS * sizeof(f16));

  fill_w<<<WFRAG_ELEMS / 256, 256, 0, stream>>>(mu, lv, wfrag);
  fill_bias<<<CC, 64, 0, stream>>>(mu, lv, beta, njk, alpha, bias);
  gmm_main<<<(NN + 127) / 128, 256, 0, stream>>>(x, ms, wfrag, bias, out);
}